// Round 2
// baseline (336.766 us; speedup 1.0000x reference)
//
#include <hip/hip_runtime.h>
#include <math.h>

#define EPS 1e-6f
constexpr int B = 8, N = 2048, C = 256, R = 4;

__device__ __forceinline__ float wred_sum(float v) {
  for (int d = 32; d; d >>= 1) v += __shfl_xor(v, d, 64);
  return v;
}
__device__ __forceinline__ float wred_max(float v) {
  for (int d = 32; d; d >>= 1) v = fmaxf(v, __shfl_xor(v, d, 64));
  return v;
}

// ---- K0: per-batch key norms: norms[b*8+0]=||write_key||, [b*8+1+r]=||read_keys[:,r]||
__global__ void k_norms(const float* __restrict__ wk, const float* __restrict__ rk,
                        float* __restrict__ norms) {
  int b = blockIdx.x, t = threadIdx.x;
  int lane = t & 63, wv = t >> 6;
  float s[5];
  {
    float v = wk[b * C + t];
    s[0] = v * v;
    float4 k4 = *(const float4*)&rk[(size_t)(b * C + t) * R];
    s[1] = k4.x * k4.x; s[2] = k4.y * k4.y; s[3] = k4.z * k4.z; s[4] = k4.w * k4.w;
  }
  __shared__ float red[4][5];
  #pragma unroll
  for (int i = 0; i < 5; i++) s[i] = wred_sum(s[i]);
  if (lane == 0) {
    #pragma unroll
    for (int i = 0; i < 5; i++) red[wv][i] = s[i];
  }
  __syncthreads();
  if (t < 5) {
    float tot = red[0][t] + red[1][t] + red[2][t] + red[3][t];
    norms[b * 8 + t] = sqrtf(tot);
  }
}

// ---- K1: retention * usage update -> u
__global__ void k_u(const float* __restrict__ usage, const float* __restrict__ wwp,
                    const float* __restrict__ fg, const float* __restrict__ rw,
                    float* __restrict__ u_) {
  int idx = blockIdx.x * 256 + threadIdx.x;
  if (idx >= B * N) return;
  int b = idx >> 11;
  float4 r4 = *(const float4*)&rw[(size_t)idx * R];
  float gx = fg[b * R + 0], gy = fg[b * R + 1], gz = fg[b * R + 2], gw2 = fg[b * R + 3];
  float psi = (1.f - gx * r4.x) * (1.f - gy * r4.y) * (1.f - gz * r4.z) * (1.f - gw2 * r4.w);
  float us = usage[idx], w = wwp[idx];
  u_[idx] = (us + w - us * w) * psi;
}

// ---- K2: per-batch bitonic argsort (stable via index tiebreak) + cumprod scan -> alloc
__global__ __launch_bounds__(1024) void k_sortalloc(const float* __restrict__ u_,
                                                    float* __restrict__ alloc_) {
  __shared__ float v[N];
  __shared__ int id[N];
  __shared__ float p[N];
  int b = blockIdx.x, t = threadIdx.x;
  int i0 = t, i1 = t + 1024;
  v[i0] = u_[b * N + i0]; id[i0] = i0;
  v[i1] = u_[b * N + i1]; id[i1] = i1;
  __syncthreads();
  for (int k = 2; k <= N; k <<= 1) {
    for (int j = k >> 1; j > 0; j >>= 1) {
      #pragma unroll
      for (int m = 0; m < 2; m++) {
        int i = t + m * 1024;
        int ixj = i ^ j;
        if (ixj > i) {
          bool up = ((i & k) == 0);
          float va = v[i], vb = v[ixj];
          int ia = id[i], ib = id[ixj];
          bool gt = (va > vb) || (va == vb && ia > ib);
          if (gt == up) { v[i] = vb; v[ixj] = va; id[i] = ib; id[ixj] = ia; }
        }
      }
      __syncthreads();
    }
  }
  p[i0] = v[i0]; p[i1] = v[i1];
  __syncthreads();
  for (int d = 1; d < N; d <<= 1) {
    float t0 = (i0 >= d) ? p[i0 - d] : 1.f;
    float t1 = (i1 >= d) ? p[i1 - d] : 1.f;
    __syncthreads();
    p[i0] *= t0; p[i1] *= t1;
    __syncthreads();
  }
  float e0 = (i0 == 0) ? 1.f : p[i0 - 1];
  float e1 = p[i1 - 1];
  alloc_[b * N + id[i0]] = (1.f - v[i0]) * e0;
  alloc_[b * N + id[i1]] = (1.f - v[i1]) * e1;
}

// ---- K3: cosine(memory, write_key)*write_strength -> sw
__global__ void k_phiw(const float* __restrict__ mem, const float* __restrict__ wk,
                       const float* __restrict__ wstr, const float* __restrict__ norms,
                       float* __restrict__ sw_) {
  int gw = (blockIdx.x * 256 + threadIdx.x) >> 6;
  int lane = threadIdx.x & 63;
  if (gw >= B * N) return;
  int b = gw >> 11, n = gw & (N - 1);
  float4 m4 = *(const float4*)&mem[(size_t)(b * N + n) * C + lane * 4];
  float4 k4 = *(const float4*)&wk[b * C + lane * 4];
  float dot = m4.x * k4.x + m4.y * k4.y + m4.z * k4.z + m4.w * k4.w;
  float nrm = m4.x * m4.x + m4.y * m4.y + m4.z * m4.z + m4.w * m4.w;
  dot = wred_sum(dot);
  nrm = wred_sum(nrm);
  if (lane == 0) {
    float phi = dot / (sqrtf(nrm) * norms[b * 8] + EPS);
    sw_[b * N + n] = phi * wstr[b];
  }
}

// ---- K4: softmax(sw) -> cw; ww = wg*(ag*alloc+(1-ag)*cw); S[r]=sum prec*rw; T[r]=sum ww*rw
__global__ __launch_bounds__(1024) void k_ww(const float* __restrict__ sw_,
    const float* __restrict__ alloc_, const float* __restrict__ ag, const float* __restrict__ wg,
    const float* __restrict__ prec, const float* __restrict__ rw,
    float* __restrict__ ww_, float* __restrict__ ST_) {
  int b = blockIdx.x, t = threadIdx.x;
  int lane = t & 63, wv = t >> 6;
  int i0 = t, i1 = t + 1024;
  __shared__ float redA[16];
  __shared__ float red8[16][8];
  float s0 = sw_[b * N + i0], s1 = sw_[b * N + i1];
  float mx = wred_max(fmaxf(s0, s1));
  if (lane == 0) redA[wv] = mx;
  __syncthreads();
  mx = redA[0];
  #pragma unroll
  for (int i = 1; i < 16; i++) mx = fmaxf(mx, redA[i]);
  float e0 = expf(s0 - mx), e1 = expf(s1 - mx);
  float sm = wred_sum(e0 + e1);
  __syncthreads();
  if (lane == 0) redA[wv] = sm;
  __syncthreads();
  sm = 0.f;
  #pragma unroll
  for (int i = 0; i < 16; i++) sm += redA[i];
  float agv = ag[b], wgv = wg[b];
  float w0 = wgv * (agv * alloc_[b * N + i0] + (1.f - agv) * (e0 / sm));
  float w1 = wgv * (agv * alloc_[b * N + i1] + (1.f - agv) * (e1 / sm));
  ww_[b * N + i0] = w0;
  ww_[b * N + i1] = w1;
  float4 r0 = *(const float4*)&rw[(size_t)(b * N + i0) * R];
  float4 r1 = *(const float4*)&rw[(size_t)(b * N + i1) * R];
  float p0 = prec[b * N + i0], p1 = prec[b * N + i1];
  float a[8] = { p0 * r0.x + p1 * r1.x, p0 * r0.y + p1 * r1.y,
                 p0 * r0.z + p1 * r1.z, p0 * r0.w + p1 * r1.w,
                 w0 * r0.x + w1 * r1.x, w0 * r0.y + w1 * r1.y,
                 w0 * r0.z + w1 * r1.z, w0 * r0.w + w1 * r1.w };
  #pragma unroll
  for (int r = 0; r < 8; r++) a[r] = wred_sum(a[r]);
  if (lane == 0) {
    #pragma unroll
    for (int r = 0; r < 8; r++) red8[wv][r] = a[r];
  }
  __syncthreads();
  if (t < 8) {
    float s = 0.f;
    for (int i = 0; i < 16; i++) s += red8[i][t];
    ST_[b * 8 + t] = s;
  }
}

// ---- K_diag: Dg[i] = (1-2ww)*link[i,i] + ww*prec[i]
__global__ void k_diag(const float* __restrict__ link, const float* __restrict__ ww_,
                       const float* __restrict__ prec, float* __restrict__ Dg_) {
  int idx = blockIdx.x * 256 + threadIdx.x;
  if (idx >= B * N) return;
  int b = idx >> 11, n = idx & (N - 1);
  float L = link[((size_t)b * N + n) * N + n];
  float w = ww_[idx];
  Dg_[idx] = (1.f - 2.f * w) * L + w * prec[idx];
}

// ---- K5: single pass over link: t = link@[rw|ww*rw] (row sums, block-complete),
//          u = link^T@[rw|ww*rw] (column partials, atomics across 64-row strips)
__global__ __launch_bounds__(256) void k_link(const float* __restrict__ link,
    const float* __restrict__ rw, const float* __restrict__ ww_,
    float* __restrict__ t_, float* __restrict__ ug_) {
  const int blk = blockIdx.x;
  const int b = blk >> 5;
  const int i0 = (blk & 31) * 64;
  const int t = threadIdx.x;
  const int lane = t & 63, wv = t >> 6;
  __shared__ float tred[64][4][8];

  const int jb0 = t * 4, jb1 = t * 4 + 1024;
  float cw[8][8];
  #pragma unroll
  for (int k = 0; k < 4; k++) {
    float4 r4 = *(const float4*)&rw[(size_t)(b * N + jb0 + k) * R];
    float w = ww_[b * N + jb0 + k];
    cw[k][0] = r4.x; cw[k][1] = r4.y; cw[k][2] = r4.z; cw[k][3] = r4.w;
    cw[k][4] = w * r4.x; cw[k][5] = w * r4.y; cw[k][6] = w * r4.z; cw[k][7] = w * r4.w;
    float4 s4 = *(const float4*)&rw[(size_t)(b * N + jb1 + k) * R];
    float v = ww_[b * N + jb1 + k];
    cw[4 + k][0] = s4.x; cw[4 + k][1] = s4.y; cw[4 + k][2] = s4.z; cw[4 + k][3] = s4.w;
    cw[4 + k][4] = v * s4.x; cw[4 + k][5] = v * s4.y; cw[4 + k][6] = v * s4.z; cw[4 + k][7] = v * s4.w;
  }
  float uacc[8][8];
  #pragma unroll
  for (int k = 0; k < 8; k++) {
    #pragma unroll
    for (int r = 0; r < 8; r++) uacc[k][r] = 0.f;
  }

  const float* Lbase = link + (size_t)(b * N + i0) * N;
  for (int ii = 0; ii < 64; ii += 4) {
    float4 La[4][2];
    #pragma unroll
    for (int m = 0; m < 4; m++) {
      const float* lr = Lbase + (size_t)(ii + m) * N;
      La[m][0] = *(const float4*)(lr + jb0);
      La[m][1] = *(const float4*)(lr + jb1);
    }
    #pragma unroll
    for (int m = 0; m < 4; m++) {
      const int i = i0 + ii + m;
      float4 q = *(const float4*)&rw[(size_t)(b * N + i) * R];
      float wi = ww_[b * N + i];
      float ri[8] = { q.x, q.y, q.z, q.w, wi * q.x, wi * q.y, wi * q.z, wi * q.w };
      float lv[8] = { La[m][0].x, La[m][0].y, La[m][0].z, La[m][0].w,
                      La[m][1].x, La[m][1].y, La[m][1].z, La[m][1].w };
      float trow[8] = { 0, 0, 0, 0, 0, 0, 0, 0 };
      #pragma unroll
      for (int k = 0; k < 8; k++) {
        #pragma unroll
        for (int r = 0; r < 8; r++) {
          uacc[k][r] = fmaf(lv[k], ri[r], uacc[k][r]);
          trow[r] = fmaf(lv[k], cw[k][r], trow[r]);
        }
      }
      // multi-value butterfly: lane l ends with total of trow[l&7] over 64 lanes
      float nv[4];
      #pragma unroll
      for (int rr = 0; rr < 4; rr++) {
        float a = trow[2 * rr], c = trow[2 * rr + 1];
        float oa = __shfl_xor(a, 1, 64), oc = __shfl_xor(c, 1, 64);
        nv[rr] = (lane & 1) ? (c + oc) : (a + oa);
      }
      float nw[2];
      #pragma unroll
      for (int rr = 0; rr < 2; rr++) {
        float a = nv[2 * rr], c = nv[2 * rr + 1];
        float oa = __shfl_xor(a, 2, 64), oc = __shfl_xor(c, 2, 64);
        nw[rr] = (lane & 2) ? (c + oc) : (a + oa);
      }
      float a2 = nw[0], c2 = nw[1];
      float oa2 = __shfl_xor(a2, 4, 64), oc2 = __shfl_xor(c2, 4, 64);
      float vv = (lane & 4) ? (c2 + oc2) : (a2 + oa2);
      vv += __shfl_xor(vv, 8, 64);
      vv += __shfl_xor(vv, 16, 64);
      vv += __shfl_xor(vv, 32, 64);
      if (lane < 8) tred[ii + m][wv][lane] = vv;
    }
  }
  __syncthreads();
  for (int o = t; o < 512; o += 256) {
    int i = o >> 3, r = o & 7;
    t_[(size_t)(b * N + i0 + i) * 8 + r] =
        tred[i][0][r] + tred[i][1][r] + tred[i][2][r] + tred[i][3][r];
  }
  #pragma unroll
  for (int k = 0; k < 8; k++) {
    int j = (k < 4) ? (jb0 + k) : (jb1 + k - 4);
    #pragma unroll
    for (int r = 0; r < 8; r++)
      atomicAdd(&ug_[(size_t)(b * N + j) * 8 + r], uacc[k][r]);
  }
}

// ---- K6: mem_new row (recomputed) -> cosine vs read_keys -> s_r[b][r][n]
__global__ void k_phir(const float* __restrict__ mem, const float* __restrict__ rk,
                       const float* __restrict__ ww_, const float* __restrict__ ev,
                       const float* __restrict__ wvec, const float* __restrict__ norms,
                       const float* __restrict__ rs, float* __restrict__ sr_) {
  int gw = (blockIdx.x * 256 + threadIdx.x) >> 6;
  int lane = threadIdx.x & 63;
  if (gw >= B * N) return;
  int b = gw >> 11, n = gw & (N - 1);
  float w = ww_[b * N + n];
  int c0 = lane * 4;
  float4 m4 = *(const float4*)&mem[(size_t)(b * N + n) * C + c0];
  float4 e4 = *(const float4*)&ev[b * C + c0];
  float4 v4 = *(const float4*)&wvec[b * C + c0];
  float mn[4] = { m4.x * (1.f - w * e4.x) + w * v4.x,
                  m4.y * (1.f - w * e4.y) + w * v4.y,
                  m4.z * (1.f - w * e4.z) + w * v4.z,
                  m4.w * (1.f - w * e4.w) + w * v4.w };
  float dot[4] = { 0, 0, 0, 0 };
  float nrm = 0.f;
  #pragma unroll
  for (int ci = 0; ci < 4; ci++) {
    float4 k4 = *(const float4*)&rk[(size_t)(b * C + c0 + ci) * R];
    dot[0] = fmaf(mn[ci], k4.x, dot[0]);
    dot[1] = fmaf(mn[ci], k4.y, dot[1]);
    dot[2] = fmaf(mn[ci], k4.z, dot[2]);
    dot[3] = fmaf(mn[ci], k4.w, dot[3]);
    nrm = fmaf(mn[ci], mn[ci], nrm);
  }
  for (int d = 32; d; d >>= 1) {
    dot[0] += __shfl_xor(dot[0], d, 64);
    dot[1] += __shfl_xor(dot[1], d, 64);
    dot[2] += __shfl_xor(dot[2], d, 64);
    dot[3] += __shfl_xor(dot[3], d, 64);
    nrm += __shfl_xor(nrm, d, 64);
  }
  if (lane == 0) {
    float mnorm = sqrtf(nrm);
    #pragma unroll
    for (int r = 0; r < 4; r++) {
      float phi = dot[r] / (mnorm * norms[b * 8 + 1 + r] + EPS);
      sr_[(size_t)(b * R + r) * N + n] = phi * rs[b * R + r];
    }
  }
}

// ---- K7: per-(b,r) softmax of s_r, fwd/bwd from t/u/Dg/S/T, combine modes -> rw_new[b][r][n]
__global__ __launch_bounds__(256) void k_rwnew(const float* __restrict__ sr_,
    const float* __restrict__ t_, const float* __restrict__ ug_, const float* __restrict__ ww_,
    const float* __restrict__ Dg_, const float* __restrict__ ST_, const float* __restrict__ prec,
    const float* __restrict__ rw, const float* __restrict__ modes, float* __restrict__ rwn_) {
  int b = blockIdx.x >> 2, r = blockIdx.x & 3;
  int t = threadIdx.x, lane = t & 63, wv = t >> 6;
  __shared__ float redA[4];
  const float* srow = sr_ + (size_t)(b * R + r) * N;
  float sv[8];
  float mx = -1e30f;
  #pragma unroll
  for (int k = 0; k < 8; k++) { sv[k] = srow[t + k * 256]; mx = fmaxf(mx, sv[k]); }
  mx = wred_max(mx);
  if (lane == 0) redA[wv] = mx;
  __syncthreads();
  mx = fmaxf(fmaxf(redA[0], redA[1]), fmaxf(redA[2], redA[3]));
  float sm = 0.f;
  #pragma unroll
  for (int k = 0; k < 8; k++) sm += expf(sv[k] - mx);
  sm = wred_sum(sm);
  __syncthreads();
  if (lane == 0) redA[wv] = sm;
  __syncthreads();
  sm = redA[0] + redA[1] + redA[2] + redA[3];
  float inv = 1.f / sm;
  float m0 = modes[(b * 3 + 0) * R + r], m1 = modes[(b * 3 + 1) * R + r],
        m2 = modes[(b * 3 + 2) * R + r];
  float S = ST_[b * 8 + r], T = ST_[b * 8 + 4 + r];
  #pragma unroll
  for (int k = 0; k < 8; k++) {
    int n = t + k * 256;
    size_t idx = (size_t)b * N + n;
    float w = ww_[idx], d = Dg_[idx], pc = prec[idx], rv = rw[idx * R + r];
    float t1 = t_[idx * 8 + r], t2 = t_[idx * 8 + 4 + r];
    float u1 = ug_[idx * 8 + r], u2 = ug_[idx * 8 + 4 + r];
    float fwd = (1.f - w) * t1 - t2 + w * S - d * rv;
    float bwd = (1.f - w) * u1 - u2 + pc * T - d * rv;
    float cr = expf(sv[k] - mx) * inv;
    rwn_[(size_t)(b * R + r) * N + n] = m0 * bwd + m1 * cr + m2 * fwd;
  }
}

// ---- K8: read_vectors partials over 64-row n-chunks (mem_new recomputed)
__global__ __launch_bounds__(256) void k_read(const float* __restrict__ mem,
    const float* __restrict__ ww_, const float* __restrict__ ev, const float* __restrict__ wvec,
    const float* __restrict__ rwn_, float* __restrict__ part_) {
  int blk = blockIdx.x;
  int b = blk >> 5, chunk = blk & 31;
  int t = threadIdx.x;
  int cg = t & 63, sub = t >> 6;
  int c0 = cg * 4;
  int nbase = chunk * 64 + sub * 16;
  float4 e4 = *(const float4*)&ev[b * C + c0];
  float4 v4 = *(const float4*)&wvec[b * C + c0];
  float acc[4][4];
  #pragma unroll
  for (int ci = 0; ci < 4; ci++) {
    #pragma unroll
    for (int r = 0; r < 4; r++) acc[ci][r] = 0.f;
  }
  for (int m = 0; m < 16; m++) {
    int n = nbase + m;
    float w = ww_[b * N + n];
    float4 m4 = *(const float4*)&mem[(size_t)(b * N + n) * C + c0];
    float mn[4] = { m4.x * (1.f - w * e4.x) + w * v4.x,
                    m4.y * (1.f - w * e4.y) + w * v4.y,
                    m4.z * (1.f - w * e4.z) + w * v4.z,
                    m4.w * (1.f - w * e4.w) + w * v4.w };
    float rv[4];
    #pragma unroll
    for (int r = 0; r < 4; r++) rv[r] = rwn_[(size_t)(b * R + r) * N + n];
    #pragma unroll
    for (int ci = 0; ci < 4; ci++) {
      #pragma unroll
      for (int r = 0; r < 4; r++) acc[ci][r] = fmaf(mn[ci], rv[r], acc[ci][r]);
    }
  }
  __shared__ float red[4][64][4][4];
  #pragma unroll
  for (int ci = 0; ci < 4; ci++) {
    #pragma unroll
    for (int r = 0; r < 4; r++) red[sub][cg][ci][r] = acc[ci][r];
  }
  __syncthreads();
  if (sub == 0) {
    #pragma unroll
    for (int ci = 0; ci < 4; ci++) {
      #pragma unroll
      for (int r = 0; r < 4; r++) {
        float s = red[0][cg][ci][r] + red[1][cg][ci][r] + red[2][cg][ci][r] + red[3][cg][ci][r];
        part_[((size_t)blk * C + (c0 + ci)) * R + r] = s;
      }
    }
  }
}

// ---- K9: reduce 32 chunk partials -> out [B][C][R]
__global__ void k_final(const float* __restrict__ part_, float* __restrict__ out) {
  int idx = blockIdx.x * 256 + threadIdx.x;
  if (idx >= B * C * R) return;
  int b = idx / (C * R), cr = idx % (C * R);
  float s = 0.f;
  for (int ch = 0; ch < 32; ch++) s += part_[(size_t)(b * 32 + ch) * C * R + cr];
  out[idx] = s;
}

extern "C" void kernel_launch(void* const* d_in, const int* in_sizes, int n_in,
                              void* d_out, int out_size, void* d_ws, size_t ws_size,
                              hipStream_t stream) {
  const float* mem   = (const float*)d_in[0];
  const float* link  = (const float*)d_in[1];
  const float* usage = (const float*)d_in[2];
  const float* rw    = (const float*)d_in[3];
  const float* wwp   = (const float*)d_in[4];
  const float* prec  = (const float*)d_in[5];
  const float* rk    = (const float*)d_in[6];
  const float* rs    = (const float*)d_in[7];
  const float* wk    = (const float*)d_in[8];
  const float* wstr  = (const float*)d_in[9];
  const float* fg    = (const float*)d_in[10];
  const float* ag    = (const float*)d_in[11];
  const float* wg    = (const float*)d_in[12];
  const float* wvec  = (const float*)d_in[13];
  const float* ev    = (const float*)d_in[14];
  const float* modes = (const float*)d_in[15];
  float* out = (float*)d_out;

  float* W = (float*)d_ws;
  float* norms = W;                 // 64
  float* u_    = W + 64;            // B*N
  float* alloc_= u_ + B * N;        // B*N
  float* sw_   = alloc_ + B * N;    // B*N
  float* ww_   = sw_ + B * N;       // B*N
  float* Dg_   = ww_ + B * N;       // B*N
  float* ST_   = Dg_ + B * N;       // 64
  float* t_    = ST_ + 64;          // B*N*8
  float* ug_   = t_ + B * N * 8;    // B*N*8
  float* sr_   = ug_ + B * N * 8;   // B*R*N
  float* rwn_  = sr_ + B * R * N;   // B*R*N
  float* part_ = rwn_ + B * R * N;  // B*32*C*R

  (void)hipMemsetAsync(ug_, 0, (size_t)B * N * 8 * sizeof(float), stream);
  k_norms<<<B, 256, 0, stream>>>(wk, rk, norms);
  k_u<<<(B * N) / 256, 256, 0, stream>>>(usage, wwp, fg, rw, u_);
  k_sortalloc<<<B, 1024, 0, stream>>>(u_, alloc_);
  k_phiw<<<(B * N) / 4, 256, 0, stream>>>(mem, wk, wstr, norms, sw_);
  k_ww<<<B, 1024, 0, stream>>>(sw_, alloc_, ag, wg, prec, rw, ww_, ST_);
  k_diag<<<(B * N) / 256, 256, 0, stream>>>(link, ww_, prec, Dg_);
  k_link<<<B * 32, 256, 0, stream>>>(link, rw, ww_, t_, ug_);
  k_phir<<<(B * N) / 4, 256, 0, stream>>>(mem, rk, ww_, ev, wvec, norms, rs, sr_);
  k_rwnew<<<B * R, 256, 0, stream>>>(sr_, t_, ug_, ww_, Dg_, ST_, prec, rw, modes, rwn_);
  k_read<<<B * 32, 256, 0, stream>>>(mem, ww_, ev, wvec, rwn_, part_);
  k_final<<<(B * C * R) / 256, 256, 0, stream>>>(part_, out);
}

// Round 3
// 150.853 us; speedup vs baseline: 2.2324x; 2.2324x over previous
//
#include <hip/hip_runtime.h>
#include <math.h>

#define EPS 1e-6f
constexpr int B = 8, N = 2048, C = 256, R = 4;

__device__ __forceinline__ float wred_sum(float v) {
  for (int d = 32; d; d >>= 1) v += __shfl_xor(v, d, 64);
  return v;
}
__device__ __forceinline__ float wred_max(float v) {
  for (int d = 32; d; d >>= 1) v = fmaxf(v, __shfl_xor(v, d, 64));
  return v;
}

// ---- K2: u computed inline, then per-batch bitonic argsort + cumprod scan -> alloc
__global__ __launch_bounds__(1024) void k_sortalloc(const float* __restrict__ usage,
    const float* __restrict__ wwp, const float* __restrict__ fg,
    const float* __restrict__ rw, float* __restrict__ alloc_) {
  __shared__ float v[N];
  __shared__ int id[N];
  __shared__ float p[N];
  int b = blockIdx.x, t = threadIdx.x;
  int i0 = t, i1 = t + 1024;
  float gx = fg[b * R + 0], gy = fg[b * R + 1], gz = fg[b * R + 2], gw2 = fg[b * R + 3];
  {
    float4 r4 = *(const float4*)&rw[(size_t)(b * N + i0) * R];
    float psi = (1.f - gx * r4.x) * (1.f - gy * r4.y) * (1.f - gz * r4.z) * (1.f - gw2 * r4.w);
    float us = usage[b * N + i0], w = wwp[b * N + i0];
    v[i0] = (us + w - us * w) * psi; id[i0] = i0;
  }
  {
    float4 r4 = *(const float4*)&rw[(size_t)(b * N + i1) * R];
    float psi = (1.f - gx * r4.x) * (1.f - gy * r4.y) * (1.f - gz * r4.z) * (1.f - gw2 * r4.w);
    float us = usage[b * N + i1], w = wwp[b * N + i1];
    v[i1] = (us + w - us * w) * psi; id[i1] = i1;
  }
  __syncthreads();
  for (int k = 2; k <= N; k <<= 1) {
    for (int j = k >> 1; j > 0; j >>= 1) {
      #pragma unroll
      for (int m = 0; m < 2; m++) {
        int i = t + m * 1024;
        int ixj = i ^ j;
        if (ixj > i) {
          bool up = ((i & k) == 0);
          float va = v[i], vb = v[ixj];
          int ia = id[i], ib = id[ixj];
          bool gt = (va > vb) || (va == vb && ia > ib);
          if (gt == up) { v[i] = vb; v[ixj] = va; id[i] = ib; id[ixj] = ia; }
        }
      }
      __syncthreads();
    }
  }
  p[i0] = v[i0]; p[i1] = v[i1];
  __syncthreads();
  for (int d = 1; d < N; d <<= 1) {
    float t0 = (i0 >= d) ? p[i0 - d] : 1.f;
    float t1 = (i1 >= d) ? p[i1 - d] : 1.f;
    __syncthreads();
    p[i0] *= t0; p[i1] *= t1;
    __syncthreads();
  }
  float e0 = (i0 == 0) ? 1.f : p[i0 - 1];
  float e1 = p[i1 - 1];
  alloc_[b * N + id[i0]] = (1.f - v[i0]) * e0;
  alloc_[b * N + id[i1]] = (1.f - v[i1]) * e1;
}

// ---- K3: cosine(memory, write_key)*write_strength -> sw (wk norm computed inline, free)
__global__ void k_phiw(const float* __restrict__ mem, const float* __restrict__ wk,
                       const float* __restrict__ wstr, float* __restrict__ sw_) {
  int gw = (blockIdx.x * 256 + threadIdx.x) >> 6;
  int lane = threadIdx.x & 63;
  if (gw >= B * N) return;
  int b = gw >> 11, n = gw & (N - 1);
  float4 m4 = *(const float4*)&mem[(size_t)(b * N + n) * C + lane * 4];
  float4 k4 = *(const float4*)&wk[b * C + lane * 4];
  float dot = m4.x * k4.x + m4.y * k4.y + m4.z * k4.z + m4.w * k4.w;
  float nrm = m4.x * m4.x + m4.y * m4.y + m4.z * m4.z + m4.w * m4.w;
  float knr = k4.x * k4.x + k4.y * k4.y + k4.z * k4.z + k4.w * k4.w;
  for (int d = 32; d; d >>= 1) {
    dot += __shfl_xor(dot, d, 64);
    nrm += __shfl_xor(nrm, d, 64);
    knr += __shfl_xor(knr, d, 64);
  }
  if (lane == 0) {
    float phi = dot / (sqrtf(nrm) * sqrtf(knr) + EPS);
    sw_[b * N + n] = phi * wstr[b];
  }
}

// ---- K4: softmax(sw) -> cw; ww = wg*(ag*alloc+(1-ag)*cw); S[r]=sum prec*rw; T[r]=sum ww*rw
__global__ __launch_bounds__(1024) void k_ww(const float* __restrict__ sw_,
    const float* __restrict__ alloc_, const float* __restrict__ ag, const float* __restrict__ wg,
    const float* __restrict__ prec, const float* __restrict__ rw,
    float* __restrict__ ww_, float* __restrict__ ST_) {
  int b = blockIdx.x, t = threadIdx.x;
  int lane = t & 63, wv = t >> 6;
  int i0 = t, i1 = t + 1024;
  __shared__ float redA[16];
  __shared__ float red8[16][8];
  float s0 = sw_[b * N + i0], s1 = sw_[b * N + i1];
  float mx = wred_max(fmaxf(s0, s1));
  if (lane == 0) redA[wv] = mx;
  __syncthreads();
  mx = redA[0];
  #pragma unroll
  for (int i = 1; i < 16; i++) mx = fmaxf(mx, redA[i]);
  float e0 = expf(s0 - mx), e1 = expf(s1 - mx);
  float sm = wred_sum(e0 + e1);
  __syncthreads();
  if (lane == 0) redA[wv] = sm;
  __syncthreads();
  sm = 0.f;
  #pragma unroll
  for (int i = 0; i < 16; i++) sm += redA[i];
  float agv = ag[b], wgv = wg[b];
  float w0 = wgv * (agv * alloc_[b * N + i0] + (1.f - agv) * (e0 / sm));
  float w1 = wgv * (agv * alloc_[b * N + i1] + (1.f - agv) * (e1 / sm));
  ww_[b * N + i0] = w0;
  ww_[b * N + i1] = w1;
  float4 r0 = *(const float4*)&rw[(size_t)(b * N + i0) * R];
  float4 r1 = *(const float4*)&rw[(size_t)(b * N + i1) * R];
  float p0 = prec[b * N + i0], p1 = prec[b * N + i1];
  float a[8] = { p0 * r0.x + p1 * r1.x, p0 * r0.y + p1 * r1.y,
                 p0 * r0.z + p1 * r1.z, p0 * r0.w + p1 * r1.w,
                 w0 * r0.x + w1 * r1.x, w0 * r0.y + w1 * r1.y,
                 w0 * r0.z + w1 * r1.z, w0 * r0.w + w1 * r1.w };
  #pragma unroll
  for (int r = 0; r < 8; r++) a[r] = wred_sum(a[r]);
  if (lane == 0) {
    #pragma unroll
    for (int r = 0; r < 8; r++) red8[wv][r] = a[r];
  }
  __syncthreads();
  if (t < 8) {
    float s = 0.f;
    for (int i = 0; i < 16; i++) s += red8[i][t];
    ST_[b * 8 + t] = s;
  }
}

// ---- K_t: row pass. t = link @ [rw | ww*rw]. 32-row strips, block-complete, no atomics.
__global__ __launch_bounds__(256) void k_t(const float* __restrict__ link,
    const float* __restrict__ rw, const float* __restrict__ ww_, float* __restrict__ t_) {
  const int blk = blockIdx.x;
  const int b = blk >> 6;
  const int i0 = (blk & 63) * 32;
  const int t = threadIdx.x;
  const int lane = t & 63, wv = t >> 6;
  __shared__ float tred[32][4][8];

  const int jb0 = t * 4, jb1 = t * 4 + 1024;
  float cw[8][8];
  #pragma unroll
  for (int k = 0; k < 4; k++) {
    float4 r4 = *(const float4*)&rw[(size_t)(b * N + jb0 + k) * R];
    float w = ww_[b * N + jb0 + k];
    cw[k][0] = r4.x; cw[k][1] = r4.y; cw[k][2] = r4.z; cw[k][3] = r4.w;
    cw[k][4] = w * r4.x; cw[k][5] = w * r4.y; cw[k][6] = w * r4.z; cw[k][7] = w * r4.w;
    float4 s4 = *(const float4*)&rw[(size_t)(b * N + jb1 + k) * R];
    float v = ww_[b * N + jb1 + k];
    cw[4 + k][0] = s4.x; cw[4 + k][1] = s4.y; cw[4 + k][2] = s4.z; cw[4 + k][3] = s4.w;
    cw[4 + k][4] = v * s4.x; cw[4 + k][5] = v * s4.y; cw[4 + k][6] = v * s4.z; cw[4 + k][7] = v * s4.w;
  }

  const float* Lbase = link + (size_t)(b * N + i0) * N;
  for (int ii = 0; ii < 32; ii += 4) {
    float4 La[4][2];
    #pragma unroll
    for (int m = 0; m < 4; m++) {
      const float* lr = Lbase + (size_t)(ii + m) * N;
      La[m][0] = *(const float4*)(lr + jb0);
      La[m][1] = *(const float4*)(lr + jb1);
    }
    #pragma unroll
    for (int m = 0; m < 4; m++) {
      float lv[8] = { La[m][0].x, La[m][0].y, La[m][0].z, La[m][0].w,
                      La[m][1].x, La[m][1].y, La[m][1].z, La[m][1].w };
      float trow[8] = { 0, 0, 0, 0, 0, 0, 0, 0 };
      #pragma unroll
      for (int k = 0; k < 8; k++) {
        #pragma unroll
        for (int r = 0; r < 8; r++) trow[r] = fmaf(lv[k], cw[k][r], trow[r]);
      }
      // butterfly: lane l ends with total of trow[l&7] over 64 lanes
      float nv[4];
      #pragma unroll
      for (int rr = 0; rr < 4; rr++) {
        float a = trow[2 * rr], c = trow[2 * rr + 1];
        float oa = __shfl_xor(a, 1, 64), oc = __shfl_xor(c, 1, 64);
        nv[rr] = (lane & 1) ? (c + oc) : (a + oa);
      }
      float nw[2];
      #pragma unroll
      for (int rr = 0; rr < 2; rr++) {
        float a = nv[2 * rr], c = nv[2 * rr + 1];
        float oa = __shfl_xor(a, 2, 64), oc = __shfl_xor(c, 2, 64);
        nw[rr] = (lane & 2) ? (c + oc) : (a + oa);
      }
      float a2 = nw[0], c2 = nw[1];
      float oa2 = __shfl_xor(a2, 4, 64), oc2 = __shfl_xor(c2, 4, 64);
      float vv = (lane & 4) ? (c2 + oc2) : (a2 + oa2);
      vv += __shfl_xor(vv, 8, 64);
      vv += __shfl_xor(vv, 16, 64);
      vv += __shfl_xor(vv, 32, 64);
      if (lane < 8) tred[ii + m][wv][lane] = vv;
    }
  }
  __syncthreads();
  {
    int i = t >> 3, r = t & 7;
    t_[(size_t)(b * N + i0 + i) * 8 + r] =
        tred[i][0][r] + tred[i][1][r] + tred[i][2][r] + tred[i][3][r];
  }
}

// ---- K_u2: column pass. u = link^T @ [rw | ww*rw]. Lane owns a column; waves split rows.
//      Block-complete (LDS reduce over 4 waves). Diagonal Dg folded in. No atomics.
__global__ __launch_bounds__(256) void k_u2(const float* __restrict__ link,
    const float* __restrict__ rw, const float* __restrict__ ww_,
    const float* __restrict__ prec, float* __restrict__ ug_, float* __restrict__ Dg_) {
  const int blk = blockIdx.x;
  const int b = blk >> 5;
  const int j0 = (blk & 31) * 64;
  const int t = threadIdx.x;
  const int lane = t & 63, wv = t >> 6;
  const int j = j0 + lane;
  __shared__ float red[4][64][8];

  float uacc[8];
  #pragma unroll
  for (int r = 0; r < 8; r++) uacc[r] = 0.f;

  const float* Lcol = link + (size_t)b * N * N + j;
  const float* rwb = rw + (size_t)b * N * R;
  const float* wwb = ww_ + (size_t)b * N;
  const int ibase = wv * 512;
  #pragma unroll 4
  for (int ii = 0; ii < 512; ii++) {
    int i = ibase + ii;
    float lv = Lcol[(size_t)i * N];
    float4 r4 = *(const float4*)&rwb[(size_t)i * R];
    float wi = wwb[i];
    uacc[0] = fmaf(lv, r4.x, uacc[0]);
    uacc[1] = fmaf(lv, r4.y, uacc[1]);
    uacc[2] = fmaf(lv, r4.z, uacc[2]);
    uacc[3] = fmaf(lv, r4.w, uacc[3]);
    uacc[4] = fmaf(lv, wi * r4.x, uacc[4]);
    uacc[5] = fmaf(lv, wi * r4.y, uacc[5]);
    uacc[6] = fmaf(lv, wi * r4.z, uacc[6]);
    uacc[7] = fmaf(lv, wi * r4.w, uacc[7]);
  }
  #pragma unroll
  for (int r = 0; r < 8; r++) red[wv][lane][r] = uacc[r];

  // diagonal correction term (wave whose row-range contains j handles it; line is cache-hot)
  if (wv == (j0 >> 9)) {
    float wj = wwb[j];
    float lv = Lcol[(size_t)j * N];
    Dg_[b * N + j] = (1.f - 2.f * wj) * lv + wj * prec[b * N + j];
  }
  __syncthreads();
  if (wv == 0) {
    float4 lo, hi;
    lo.x = red[0][lane][0] + red[1][lane][0] + red[2][lane][0] + red[3][lane][0];
    lo.y = red[0][lane][1] + red[1][lane][1] + red[2][lane][1] + red[3][lane][1];
    lo.z = red[0][lane][2] + red[1][lane][2] + red[2][lane][2] + red[3][lane][2];
    lo.w = red[0][lane][3] + red[1][lane][3] + red[2][lane][3] + red[3][lane][3];
    hi.x = red[0][lane][4] + red[1][lane][4] + red[2][lane][4] + red[3][lane][4];
    hi.y = red[0][lane][5] + red[1][lane][5] + red[2][lane][5] + red[3][lane][5];
    hi.z = red[0][lane][6] + red[1][lane][6] + red[2][lane][6] + red[3][lane][6];
    hi.w = red[0][lane][7] + red[1][lane][7] + red[2][lane][7] + red[3][lane][7];
    *(float4*)&ug_[(size_t)(b * N + j) * 8] = lo;
    *(float4*)&ug_[(size_t)(b * N + j) * 8 + 4] = hi;
  }
}

// ---- K6: mem_new row (recomputed) -> cosine vs read_keys -> s_r[b][r][n] (rk norms inline)
__global__ void k_phir(const float* __restrict__ mem, const float* __restrict__ rk,
                       const float* __restrict__ ww_, const float* __restrict__ ev,
                       const float* __restrict__ wvec, const float* __restrict__ rs,
                       float* __restrict__ sr_) {
  int gw = (blockIdx.x * 256 + threadIdx.x) >> 6;
  int lane = threadIdx.x & 63;
  if (gw >= B * N) return;
  int b = gw >> 11, n = gw & (N - 1);
  float w = ww_[b * N + n];
  int c0 = lane * 4;
  float4 m4 = *(const float4*)&mem[(size_t)(b * N + n) * C + c0];
  float4 e4 = *(const float4*)&ev[b * C + c0];
  float4 v4 = *(const float4*)&wvec[b * C + c0];
  float mn[4] = { m4.x * (1.f - w * e4.x) + w * v4.x,
                  m4.y * (1.f - w * e4.y) + w * v4.y,
                  m4.z * (1.f - w * e4.z) + w * v4.z,
                  m4.w * (1.f - w * e4.w) + w * v4.w };
  float dot[4] = { 0, 0, 0, 0 };
  float kn[4] = { 0, 0, 0, 0 };
  float nrm = 0.f;
  #pragma unroll
  for (int ci = 0; ci < 4; ci++) {
    float4 k4 = *(const float4*)&rk[(size_t)(b * C + c0 + ci) * R];
    dot[0] = fmaf(mn[ci], k4.x, dot[0]);
    dot[1] = fmaf(mn[ci], k4.y, dot[1]);
    dot[2] = fmaf(mn[ci], k4.z, dot[2]);
    dot[3] = fmaf(mn[ci], k4.w, dot[3]);
    kn[0] = fmaf(k4.x, k4.x, kn[0]);
    kn[1] = fmaf(k4.y, k4.y, kn[1]);
    kn[2] = fmaf(k4.z, k4.z, kn[2]);
    kn[3] = fmaf(k4.w, k4.w, kn[3]);
    nrm = fmaf(mn[ci], mn[ci], nrm);
  }
  for (int d = 32; d; d >>= 1) {
    dot[0] += __shfl_xor(dot[0], d, 64);
    dot[1] += __shfl_xor(dot[1], d, 64);
    dot[2] += __shfl_xor(dot[2], d, 64);
    dot[3] += __shfl_xor(dot[3], d, 64);
    kn[0] += __shfl_xor(kn[0], d, 64);
    kn[1] += __shfl_xor(kn[1], d, 64);
    kn[2] += __shfl_xor(kn[2], d, 64);
    kn[3] += __shfl_xor(kn[3], d, 64);
    nrm += __shfl_xor(nrm, d, 64);
  }
  if (lane == 0) {
    float mnorm = sqrtf(nrm);
    #pragma unroll
    for (int r = 0; r < 4; r++) {
      float phi = dot[r] / (mnorm * sqrtf(kn[r]) + EPS);
      sr_[(size_t)(b * R + r) * N + n] = phi * rs[b * R + r];
    }
  }
}

// ---- K7: per-(b,r) softmax of s_r, fwd/bwd from t/u/Dg/S/T, combine modes -> rw_new[b][r][n]
__global__ __launch_bounds__(256) void k_rwnew(const float* __restrict__ sr_,
    const float* __restrict__ t_, const float* __restrict__ ug_, const float* __restrict__ ww_,
    const float* __restrict__ Dg_, const float* __restrict__ ST_, const float* __restrict__ prec,
    const float* __restrict__ rw, const float* __restrict__ modes, float* __restrict__ rwn_) {
  int b = blockIdx.x >> 2, r = blockIdx.x & 3;
  int t = threadIdx.x, lane = t & 63, wv = t >> 6;
  __shared__ float redA[4];
  const float* srow = sr_ + (size_t)(b * R + r) * N;
  float sv[8];
  float mx = -1e30f;
  #pragma unroll
  for (int k = 0; k < 8; k++) { sv[k] = srow[t + k * 256]; mx = fmaxf(mx, sv[k]); }
  mx = wred_max(mx);
  if (lane == 0) redA[wv] = mx;
  __syncthreads();
  mx = fmaxf(fmaxf(redA[0], redA[1]), fmaxf(redA[2], redA[3]));
  float sm = 0.f;
  #pragma unroll
  for (int k = 0; k < 8; k++) sm += expf(sv[k] - mx);
  sm = wred_sum(sm);
  __syncthreads();
  if (lane == 0) redA[wv] = sm;
  __syncthreads();
  sm = redA[0] + redA[1] + redA[2] + redA[3];
  float inv = 1.f / sm;
  float m0 = modes[(b * 3 + 0) * R + r], m1 = modes[(b * 3 + 1) * R + r],
        m2 = modes[(b * 3 + 2) * R + r];
  float S = ST_[b * 8 + r], T = ST_[b * 8 + 4 + r];
  #pragma unroll
  for (int k = 0; k < 8; k++) {
    int n = t + k * 256;
    size_t idx = (size_t)b * N + n;
    float w = ww_[idx], d = Dg_[idx], pc = prec[idx], rv = rw[idx * R + r];
    float t1 = t_[idx * 8 + r], t2 = t_[idx * 8 + 4 + r];
    float u1 = ug_[idx * 8 + r], u2 = ug_[idx * 8 + 4 + r];
    float fwd = (1.f - w) * t1 - t2 + w * S - d * rv;
    float bwd = (1.f - w) * u1 - u2 + pc * T - d * rv;
    float cr = expf(sv[k] - mx) * inv;
    rwn_[(size_t)(b * R + r) * N + n] = m0 * bwd + m1 * cr + m2 * fwd;
  }
}

// ---- K8: read_vectors partials over 64-row n-chunks (mem_new recomputed)
__global__ __launch_bounds__(256) void k_read(const float* __restrict__ mem,
    const float* __restrict__ ww_, const float* __restrict__ ev, const float* __restrict__ wvec,
    const float* __restrict__ rwn_, float* __restrict__ part_) {
  int blk = blockIdx.x;
  int b = blk >> 5, chunk = blk & 31;
  int t = threadIdx.x;
  int cg = t & 63, sub = t >> 6;
  int c0 = cg * 4;
  int nbase = chunk * 64 + sub * 16;
  float4 e4 = *(const float4*)&ev[b * C + c0];
  float4 v4 = *(const float4*)&wvec[b * C + c0];
  float acc[4][4];
  #pragma unroll
  for (int ci = 0; ci < 4; ci++) {
    #pragma unroll
    for (int r = 0; r < 4; r++) acc[ci][r] = 0.f;
  }
  for (int m = 0; m < 16; m++) {
    int n = nbase + m;
    float w = ww_[b * N + n];
    float4 m4 = *(const float4*)&mem[(size_t)(b * N + n) * C + c0];
    float mn[4] = { m4.x * (1.f - w * e4.x) + w * v4.x,
                    m4.y * (1.f - w * e4.y) + w * v4.y,
                    m4.z * (1.f - w * e4.z) + w * v4.z,
                    m4.w * (1.f - w * e4.w) + w * v4.w };
    float rv[4];
    #pragma unroll
    for (int r = 0; r < 4; r++) rv[r] = rwn_[(size_t)(b * R + r) * N + n];
    #pragma unroll
    for (int ci = 0; ci < 4; ci++) {
      #pragma unroll
      for (int r = 0; r < 4; r++) acc[ci][r] = fmaf(mn[ci], rv[r], acc[ci][r]);
    }
  }
  __shared__ float red[4][64][4][4];
  #pragma unroll
  for (int ci = 0; ci < 4; ci++) {
    #pragma unroll
    for (int r = 0; r < 4; r++) red[sub][cg][ci][r] = acc[ci][r];
  }
  __syncthreads();
  if (sub == 0) {
    #pragma unroll
    for (int ci = 0; ci < 4; ci++) {
      #pragma unroll
      for (int r = 0; r < 4; r++) {
        float s = red[0][cg][ci][r] + red[1][cg][ci][r] + red[2][cg][ci][r] + red[3][cg][ci][r];
        part_[((size_t)blk * C + (c0 + ci)) * R + r] = s;
      }
    }
  }
}

// ---- K9: reduce 32 chunk partials -> out [B][C][R]
__global__ void k_final(const float* __restrict__ part_, float* __restrict__ out) {
  int idx = blockIdx.x * 256 + threadIdx.x;
  if (idx >= B * C * R) return;
  int b = idx / (C * R), cr = idx % (C * R);
  float s = 0.f;
  for (int ch = 0; ch < 32; ch++) s += part_[(size_t)(b * 32 + ch) * C * R + cr];
  out[idx] = s;
}

extern "C" void kernel_launch(void* const* d_in, const int* in_sizes, int n_in,
                              void* d_out, int out_size, void* d_ws, size_t ws_size,
                              hipStream_t stream) {
  const float* mem   = (const float*)d_in[0];
  const float* link  = (const float*)d_in[1];
  const float* usage = (const float*)d_in[2];
  const float* rw    = (const float*)d_in[3];
  const float* wwp   = (const float*)d_in[4];
  const float* prec  = (const float*)d_in[5];
  const float* rk    = (const float*)d_in[6];
  const float* rs    = (const float*)d_in[7];
  const float* wk    = (const float*)d_in[8];
  const float* wstr  = (const float*)d_in[9];
  const float* fg    = (const float*)d_in[10];
  const float* ag    = (const float*)d_in[11];
  const float* wg    = (const float*)d_in[12];
  const float* wvec  = (const float*)d_in[13];
  const float* ev    = (const float*)d_in[14];
  const float* modes = (const float*)d_in[15];
  float* out = (float*)d_out;

  float* W = (float*)d_ws;
  float* alloc_= W;                 // B*N
  float* sw_   = alloc_ + B * N;    // B*N
  float* ww_   = sw_ + B * N;       // B*N
  float* Dg_   = ww_ + B * N;       // B*N
  float* ST_   = Dg_ + B * N;       // 64
  float* t_    = ST_ + 64;          // B*N*8
  float* ug_   = t_ + B * N * 8;    // B*N*8
  float* sr_   = ug_ + B * N * 8;   // B*R*N
  float* rwn_  = sr_ + B * R * N;   // B*R*N
  float* part_ = rwn_ + B * R * N;  // B*32*C*R

  k_sortalloc<<<B, 1024, 0, stream>>>(usage, wwp, fg, rw, alloc_);
  k_phiw<<<(B * N) / 4, 256, 0, stream>>>(mem, wk, wstr, sw_);
  k_ww<<<B, 1024, 0, stream>>>(sw_, alloc_, ag, wg, prec, rw, ww_, ST_);
  k_t<<<B * 64, 256, 0, stream>>>(link, rw, ww_, t_);
  k_u2<<<B * 32, 256, 0, stream>>>(link, rw, ww_, prec, ug_, Dg_);
  k_phir<<<(B * N) / 4, 256, 0, stream>>>(mem, rk, ww_, ev, wvec, rs, sr_);
  k_rwnew<<<B * R, 256, 0, stream>>>(sr_, t_, ug_, ww_, Dg_, ST_, prec, rw, modes, rwn_);
  k_read<<<B * 32, 256, 0, stream>>>(mem, ww_, ev, wvec, rwn_, part_);
  k_final<<<(B * C * R) / 256, 256, 0, stream>>>(part_, out);
}

// Round 4
// 112.682 us; speedup vs baseline: 2.9887x; 1.3388x over previous
//
#include <hip/hip_runtime.h>
#include <math.h>

#define EPS 1e-6f
constexpr int B = 8, N = 2048, C = 256, R = 4;

__device__ __forceinline__ float wred_sum(float v) {
  for (int d = 32; d; d >>= 1) v += __shfl_xor(v, d, 64);
  return v;
}
__device__ __forceinline__ float wred_max(float v) {
  for (int d = 32; d; d >>= 1) v = fmaxf(v, __shfl_xor(v, d, 64));
  return v;
}

// ---- K_alloc: sort-free allocation weighting.
// alloc_i = (1-u_i) * exp2( sum_{j: u_j<u_i or (u_j==u_i && j<i)} log2(u_j) )
// == (1-u_sorted)*exclusive-cumprod in stable ascending order.
__global__ __launch_bounds__(1024) void k_alloc(const float* __restrict__ usage,
    const float* __restrict__ wwp, const float* __restrict__ fg,
    const float* __restrict__ rw, float* __restrict__ alloc_) {
  __shared__ float2 ulg[N];      // (u, log2(u)) 16KB
  __shared__ float Sp[4][256];
  int blk = blockIdx.x;
  int b = blk >> 3, chunk = blk & 7;
  int t = threadIdx.x;
  float gx = fg[b * R + 0], gy = fg[b * R + 1], gz = fg[b * R + 2], gw2 = fg[b * R + 3];
  for (int e = t; e < N; e += 1024) {
    float4 r4 = *(const float4*)&rw[(size_t)(b * N + e) * R];
    float psi = (1.f - gx * r4.x) * (1.f - gy * r4.y) * (1.f - gz * r4.z) * (1.f - gw2 * r4.w);
    float us = usage[b * N + e], w = wwp[b * N + e];
    float u = (us + w - us * w) * psi;
    ulg[e] = make_float2(u, log2f(u));
  }
  __syncthreads();
  int i = chunk * 256 + (t & 255);
  int jseg = t >> 8;
  float ui = ulg[i].x;
  float S = 0.f;
  int j0 = jseg * 512;
  #pragma unroll 4
  for (int jj = 0; jj < 512; jj++) {
    int j = j0 + jj;
    float2 v = ulg[j];
    bool sel = (v.x < ui) || (v.x == ui && j < i);
    S += sel ? v.y : 0.f;
  }
  Sp[jseg][t & 255] = S;
  __syncthreads();
  if (t < 256) {
    float tot = Sp[0][t] + Sp[1][t] + Sp[2][t] + Sp[3][t];
    int ii = chunk * 256 + t;
    alloc_[b * N + ii] = (1.f - ulg[ii].x) * exp2f(tot);
  }
}

// ---- K3: cosine(memory, write_key)*write_strength -> sw
__global__ void k_phiw(const float* __restrict__ mem, const float* __restrict__ wk,
                       const float* __restrict__ wstr, float* __restrict__ sw_) {
  int gw = (blockIdx.x * 256 + threadIdx.x) >> 6;
  int lane = threadIdx.x & 63;
  if (gw >= B * N) return;
  int b = gw >> 11, n = gw & (N - 1);
  float4 m4 = *(const float4*)&mem[(size_t)(b * N + n) * C + lane * 4];
  float4 k4 = *(const float4*)&wk[b * C + lane * 4];
  float dot = m4.x * k4.x + m4.y * k4.y + m4.z * k4.z + m4.w * k4.w;
  float nrm = m4.x * m4.x + m4.y * m4.y + m4.z * m4.z + m4.w * m4.w;
  float knr = k4.x * k4.x + k4.y * k4.y + k4.z * k4.z + k4.w * k4.w;
  for (int d = 32; d; d >>= 1) {
    dot += __shfl_xor(dot, d, 64);
    nrm += __shfl_xor(nrm, d, 64);
    knr += __shfl_xor(knr, d, 64);
  }
  if (lane == 0) {
    float phi = dot / (sqrtf(nrm) * sqrtf(knr) + EPS);
    sw_[b * N + n] = phi * wstr[b];
  }
}

// ---- K4: softmax(sw) -> cw; ww = wg*(ag*alloc+(1-ag)*cw); S[r]=sum prec*rw; T[r]=sum ww*rw
__global__ __launch_bounds__(1024) void k_ww(const float* __restrict__ sw_,
    const float* __restrict__ alloc_, const float* __restrict__ ag, const float* __restrict__ wg,
    const float* __restrict__ prec, const float* __restrict__ rw,
    float* __restrict__ ww_, float* __restrict__ ST_) {
  int b = blockIdx.x, t = threadIdx.x;
  int lane = t & 63, wv = t >> 6;
  int i0 = t, i1 = t + 1024;
  __shared__ float redA[16];
  __shared__ float red8[16][8];
  float s0 = sw_[b * N + i0], s1 = sw_[b * N + i1];
  float mx = wred_max(fmaxf(s0, s1));
  if (lane == 0) redA[wv] = mx;
  __syncthreads();
  mx = redA[0];
  #pragma unroll
  for (int i = 1; i < 16; i++) mx = fmaxf(mx, redA[i]);
  float e0 = expf(s0 - mx), e1 = expf(s1 - mx);
  float sm = wred_sum(e0 + e1);
  __syncthreads();
  if (lane == 0) redA[wv] = sm;
  __syncthreads();
  sm = 0.f;
  #pragma unroll
  for (int i = 0; i < 16; i++) sm += redA[i];
  float agv = ag[b], wgv = wg[b];
  float w0 = wgv * (agv * alloc_[b * N + i0] + (1.f - agv) * (e0 / sm));
  float w1 = wgv * (agv * alloc_[b * N + i1] + (1.f - agv) * (e1 / sm));
  ww_[b * N + i0] = w0;
  ww_[b * N + i1] = w1;
  float4 r0 = *(const float4*)&rw[(size_t)(b * N + i0) * R];
  float4 r1 = *(const float4*)&rw[(size_t)(b * N + i1) * R];
  float p0 = prec[b * N + i0], p1 = prec[b * N + i1];
  float a[8] = { p0 * r0.x + p1 * r1.x, p0 * r0.y + p1 * r1.y,
                 p0 * r0.z + p1 * r1.z, p0 * r0.w + p1 * r1.w,
                 w0 * r0.x + w1 * r1.x, w0 * r0.y + w1 * r1.y,
                 w0 * r0.z + w1 * r1.z, w0 * r0.w + w1 * r1.w };
  #pragma unroll
  for (int r = 0; r < 8; r++) a[r] = wred_sum(a[r]);
  if (lane == 0) {
    #pragma unroll
    for (int r = 0; r < 8; r++) red8[wv][r] = a[r];
  }
  __syncthreads();
  if (t < 8) {
    float s = 0.f;
    for (int i = 0; i < 16; i++) s += red8[i][t];
    ST_[b * 8 + t] = s;
  }
}

// ---- K_linkpass: ONE pass over link. 64-row strips (32/batch, 256 blocks, 512 thr).
//  t rows complete (butterfly); u column-partials per strip -> upart (no atomics).
__global__ __launch_bounds__(512) void k_linkpass(const float* __restrict__ link,
    const float* __restrict__ rw, const float* __restrict__ ww_,
    float* __restrict__ t_, float* __restrict__ upart) {
  const int blk = blockIdx.x;
  const int b = blk >> 5;
  const int strip = blk & 31;
  const int i0 = strip * 64;
  const int t = threadIdx.x;          // 0..511
  const int lane = t & 63, wv = t >> 6;
  const int jb = t * 4;               // 4 columns per thread
  __shared__ float tred[64][8][8];    // 16KB

  float cw[4][8];
  #pragma unroll
  for (int k = 0; k < 4; k++) {
    float4 r4 = *(const float4*)&rw[(size_t)(b * N + jb + k) * R];
    float w = ww_[b * N + jb + k];
    cw[k][0] = r4.x; cw[k][1] = r4.y; cw[k][2] = r4.z; cw[k][3] = r4.w;
    cw[k][4] = w * r4.x; cw[k][5] = w * r4.y; cw[k][6] = w * r4.z; cw[k][7] = w * r4.w;
  }
  float uacc[4][8];
  #pragma unroll
  for (int k = 0; k < 4; k++) {
    #pragma unroll
    for (int r = 0; r < 8; r++) uacc[k][r] = 0.f;
  }

  const float* Lbase = link + (size_t)(b * N + i0) * N;
  for (int ii = 0; ii < 64; ii += 4) {
    float4 La[4];
    #pragma unroll
    for (int m = 0; m < 4; m++)
      La[m] = *(const float4*)(Lbase + (size_t)(ii + m) * N + jb);
    #pragma unroll
    for (int m = 0; m < 4; m++) {
      const int i = i0 + ii + m;
      float4 q = *(const float4*)&rw[(size_t)(b * N + i) * R];   // uniform -> scalar
      float wi = ww_[b * N + i];
      float ri[8] = { q.x, q.y, q.z, q.w, wi * q.x, wi * q.y, wi * q.z, wi * q.w };
      float lv[4] = { La[m].x, La[m].y, La[m].z, La[m].w };
      float trow[8] = { 0, 0, 0, 0, 0, 0, 0, 0 };
      #pragma unroll
      for (int k = 0; k < 4; k++) {
        #pragma unroll
        for (int r = 0; r < 8; r++) {
          uacc[k][r] = fmaf(lv[k], ri[r], uacc[k][r]);
          trow[r] = fmaf(lv[k], cw[k][r], trow[r]);
        }
      }
      // butterfly: lane l ends with sum over 64 lanes of trow[l&7]
      float nv[4];
      #pragma unroll
      for (int rr = 0; rr < 4; rr++) {
        float a = trow[2 * rr], c = trow[2 * rr + 1];
        float oa = __shfl_xor(a, 1, 64), oc = __shfl_xor(c, 1, 64);
        nv[rr] = (lane & 1) ? (c + oc) : (a + oa);
      }
      float nw[2];
      #pragma unroll
      for (int rr = 0; rr < 2; rr++) {
        float a = nv[2 * rr], c = nv[2 * rr + 1];
        float oa = __shfl_xor(a, 2, 64), oc = __shfl_xor(c, 2, 64);
        nw[rr] = (lane & 2) ? (c + oc) : (a + oa);
      }
      float a2 = nw[0], c2 = nw[1];
      float oa2 = __shfl_xor(a2, 4, 64), oc2 = __shfl_xor(c2, 4, 64);
      float vv = (lane & 4) ? (c2 + oc2) : (a2 + oa2);
      vv += __shfl_xor(vv, 8, 64);
      vv += __shfl_xor(vv, 16, 64);
      vv += __shfl_xor(vv, 32, 64);
      if (lane < 8) tred[ii + m][wv][lane] = vv;
    }
  }
  __syncthreads();
  {
    int i = t >> 3, r = t & 7;
    float s = 0.f;
    #pragma unroll
    for (int w8 = 0; w8 < 8; w8++) s += tred[i][w8][r];
    t_[(size_t)(b * N + i0 + i) * 8 + r] = s;
  }
  // u partials: upart[b][strip][j][8], contiguous 128B per thread
  float* ub = upart + ((size_t)(b * 32 + strip) * N + jb) * 8;
  #pragma unroll
  for (int k = 0; k < 4; k++) {
    float4 lo = { uacc[k][0], uacc[k][1], uacc[k][2], uacc[k][3] };
    float4 hi = { uacc[k][4], uacc[k][5], uacc[k][6], uacc[k][7] };
    *(float4*)(ub + k * 8) = lo;
    *(float4*)(ub + k * 8 + 4) = hi;
  }
}

// ---- K6: mem_new row (recomputed) -> cosine vs read_keys -> s_r[b][r][n]
__global__ void k_phir(const float* __restrict__ mem, const float* __restrict__ rk,
                       const float* __restrict__ ww_, const float* __restrict__ ev,
                       const float* __restrict__ wvec, const float* __restrict__ rs,
                       float* __restrict__ sr_) {
  int gw = (blockIdx.x * 256 + threadIdx.x) >> 6;
  int lane = threadIdx.x & 63;
  if (gw >= B * N) return;
  int b = gw >> 11, n = gw & (N - 1);
  float w = ww_[b * N + n];
  int c0 = lane * 4;
  float4 m4 = *(const float4*)&mem[(size_t)(b * N + n) * C + c0];
  float4 e4 = *(const float4*)&ev[b * C + c0];
  float4 v4 = *(const float4*)&wvec[b * C + c0];
  float mn[4] = { m4.x * (1.f - w * e4.x) + w * v4.x,
                  m4.y * (1.f - w * e4.y) + w * v4.y,
                  m4.z * (1.f - w * e4.z) + w * v4.z,
                  m4.w * (1.f - w * e4.w) + w * v4.w };
  float dot[4] = { 0, 0, 0, 0 };
  float kn[4] = { 0, 0, 0, 0 };
  float nrm = 0.f;
  #pragma unroll
  for (int ci = 0; ci < 4; ci++) {
    float4 k4 = *(const float4*)&rk[(size_t)(b * C + c0 + ci) * R];
    dot[0] = fmaf(mn[ci], k4.x, dot[0]);
    dot[1] = fmaf(mn[ci], k4.y, dot[1]);
    dot[2] = fmaf(mn[ci], k4.z, dot[2]);
    dot[3] = fmaf(mn[ci], k4.w, dot[3]);
    kn[0] = fmaf(k4.x, k4.x, kn[0]);
    kn[1] = fmaf(k4.y, k4.y, kn[1]);
    kn[2] = fmaf(k4.z, k4.z, kn[2]);
    kn[3] = fmaf(k4.w, k4.w, kn[3]);
    nrm = fmaf(mn[ci], mn[ci], nrm);
  }
  for (int d = 32; d; d >>= 1) {
    dot[0] += __shfl_xor(dot[0], d, 64);
    dot[1] += __shfl_xor(dot[1], d, 64);
    dot[2] += __shfl_xor(dot[2], d, 64);
    dot[3] += __shfl_xor(dot[3], d, 64);
    kn[0] += __shfl_xor(kn[0], d, 64);
    kn[1] += __shfl_xor(kn[1], d, 64);
    kn[2] += __shfl_xor(kn[2], d, 64);
    kn[3] += __shfl_xor(kn[3], d, 64);
    nrm += __shfl_xor(nrm, d, 64);
  }
  if (lane == 0) {
    float mnorm = sqrtf(nrm);
    #pragma unroll
    for (int r = 0; r < 4; r++) {
      float phi = dot[r] / (mnorm * sqrtf(kn[r]) + EPS);
      sr_[(size_t)(b * R + r) * N + n] = phi * rs[b * R + r];
    }
  }
}

// ---- K_smax: per-(b,r) softmax max+denominator over n
__global__ __launch_bounds__(256) void k_smax(const float* __restrict__ sr_,
                                              float* __restrict__ smax_) {
  int b = blockIdx.x >> 2, r = blockIdx.x & 3;
  int t = threadIdx.x, lane = t & 63, wv = t >> 6;
  __shared__ float redA[4];
  const float* srow = sr_ + (size_t)(b * R + r) * N;
  float sv[8];
  float mx = -1e30f;
  #pragma unroll
  for (int k = 0; k < 8; k++) { sv[k] = srow[t + k * 256]; mx = fmaxf(mx, sv[k]); }
  mx = wred_max(mx);
  if (lane == 0) redA[wv] = mx;
  __syncthreads();
  mx = fmaxf(fmaxf(redA[0], redA[1]), fmaxf(redA[2], redA[3]));
  float sm = 0.f;
  #pragma unroll
  for (int k = 0; k < 8; k++) sm += expf(sv[k] - mx);
  sm = wred_sum(sm);
  __syncthreads();
  if (lane == 0) redA[wv] = sm;
  __syncthreads();
  if (t == 0) {
    smax_[(b * R + r) * 2] = mx;
    smax_[(b * R + r) * 2 + 1] = redA[0] + redA[1] + redA[2] + redA[3];
  }
}

// ---- K_comb: reduce upart strips, diag from link, softmax-normalize, modes -> rwn
__global__ __launch_bounds__(64) void k_comb(const float* __restrict__ link,
    const float* __restrict__ sr_, const float* __restrict__ t_,
    const float* __restrict__ upart, const float* __restrict__ ww_,
    const float* __restrict__ prec, const float* __restrict__ rw,
    const float* __restrict__ ST_, const float* __restrict__ smax_,
    const float* __restrict__ modes, float* __restrict__ rwn_) {
  int id = blockIdx.x * 64 + threadIdx.x;
  int b = id >> 11, n = id & (N - 1);
  float u1[4] = { 0, 0, 0, 0 }, u2[4] = { 0, 0, 0, 0 };
  const float* up = upart + ((size_t)(b * 32) * N + n) * 8;
  #pragma unroll 8
  for (int s = 0; s < 32; s++) {
    const float* p = up + (size_t)s * N * 8;
    float4 a = *(const float4*)p;
    float4 c = *(const float4*)(p + 4);
    u1[0] += a.x; u1[1] += a.y; u1[2] += a.z; u1[3] += a.w;
    u2[0] += c.x; u2[1] += c.y; u2[2] += c.z; u2[3] += c.w;
  }
  float4 t1 = *(const float4*)&t_[(size_t)id * 8];
  float4 t2 = *(const float4*)&t_[(size_t)id * 8 + 4];
  float tt1[4] = { t1.x, t1.y, t1.z, t1.w };
  float tt2[4] = { t2.x, t2.y, t2.z, t2.w };
  float w = ww_[id], pc = prec[id];
  float L = link[(size_t)(b * N + n) * N + n];
  float Dg = (1.f - 2.f * w) * L + w * pc;
  float4 rv4 = *(const float4*)&rw[(size_t)id * R];
  float rv[4] = { rv4.x, rv4.y, rv4.z, rv4.w };
  #pragma unroll
  for (int r = 0; r < 4; r++) {
    float m0 = modes[(b * 3 + 0) * R + r], m1 = modes[(b * 3 + 1) * R + r],
          m2 = modes[(b * 3 + 2) * R + r];
    float S = ST_[b * 8 + r], T = ST_[b * 8 + 4 + r];
    float mx = smax_[(b * R + r) * 2], inv = 1.f / smax_[(b * R + r) * 2 + 1];
    float sv = sr_[(size_t)(b * R + r) * N + n];
    float cr = expf(sv - mx) * inv;
    float fwd = (1.f - w) * tt1[r] - tt2[r] + w * S - Dg * rv[r];
    float bwd = (1.f - w) * u1[r] - u2[r] + pc * T - Dg * rv[r];
    rwn_[(size_t)(b * R + r) * N + n] = m0 * bwd + m1 * cr + m2 * fwd;
  }
}

// ---- K8: read_vectors partials over 64-row n-chunks (mem_new recomputed)
__global__ __launch_bounds__(256) void k_read(const float* __restrict__ mem,
    const float* __restrict__ ww_, const float* __restrict__ ev, const float* __restrict__ wvec,
    const float* __restrict__ rwn_, float* __restrict__ part_) {
  int blk = blockIdx.x;
  int b = blk >> 5, chunk = blk & 31;
  int t = threadIdx.x;
  int cg = t & 63, sub = t >> 6;
  int c0 = cg * 4;
  int nbase = chunk * 64 + sub * 16;
  float4 e4 = *(const float4*)&ev[b * C + c0];
  float4 v4 = *(const float4*)&wvec[b * C + c0];
  float acc[4][4];
  #pragma unroll
  for (int ci = 0; ci < 4; ci++) {
    #pragma unroll
    for (int r = 0; r < 4; r++) acc[ci][r] = 0.f;
  }
  for (int m = 0; m < 16; m++) {
    int n = nbase + m;
    float w = ww_[b * N + n];
    float4 m4 = *(const float4*)&mem[(size_t)(b * N + n) * C + c0];
    float mn[4] = { m4.x * (1.f - w * e4.x) + w * v4.x,
                    m4.y * (1.f - w * e4.y) + w * v4.y,
                    m4.z * (1.f - w * e4.z) + w * v4.z,
                    m4.w * (1.f - w * e4.w) + w * v4.w };
    float rv[4];
    #pragma unroll
    for (int r = 0; r < 4; r++) rv[r] = rwn_[(size_t)(b * R + r) * N + n];
    #pragma unroll
    for (int ci = 0; ci < 4; ci++) {
      #pragma unroll
      for (int r = 0; r < 4; r++) acc[ci][r] = fmaf(mn[ci], rv[r], acc[ci][r]);
    }
  }
  __shared__ float red[4][64][4][4];
  #pragma unroll
  for (int ci = 0; ci < 4; ci++) {
    #pragma unroll
    for (int r = 0; r < 4; r++) red[sub][cg][ci][r] = acc[ci][r];
  }
  __syncthreads();
  if (sub == 0) {
    #pragma unroll
    for (int ci = 0; ci < 4; ci++) {
      #pragma unroll
      for (int r = 0; r < 4; r++) {
        float s = red[0][cg][ci][r] + red[1][cg][ci][r] + red[2][cg][ci][r] + red[3][cg][ci][r];
        part_[((size_t)blk * C + (c0 + ci)) * R + r] = s;
      }
    }
  }
}

// ---- K9: reduce 32 chunk partials -> out [B][C][R]
__global__ void k_final(const float* __restrict__ part_, float* __restrict__ out) {
  int idx = blockIdx.x * 256 + threadIdx.x;
  if (idx >= B * C * R) return;
  int b = idx / (C * R), cr = idx % (C * R);
  float s = 0.f;
  for (int ch = 0; ch < 32; ch++) s += part_[(size_t)(b * 32 + ch) * C * R + cr];
  out[idx] = s;
}

extern "C" void kernel_launch(void* const* d_in, const int* in_sizes, int n_in,
                              void* d_out, int out_size, void* d_ws, size_t ws_size,
                              hipStream_t stream) {
  const float* mem   = (const float*)d_in[0];
  const float* link  = (const float*)d_in[1];
  const float* usage = (const float*)d_in[2];
  const float* rw    = (const float*)d_in[3];
  const float* wwp   = (const float*)d_in[4];
  const float* prec  = (const float*)d_in[5];
  const float* rk    = (const float*)d_in[6];
  const float* rs    = (const float*)d_in[7];
  const float* wk    = (const float*)d_in[8];
  const float* wstr  = (const float*)d_in[9];
  const float* fg    = (const float*)d_in[10];
  const float* ag    = (const float*)d_in[11];
  const float* wg    = (const float*)d_in[12];
  const float* wvec  = (const float*)d_in[13];
  const float* ev    = (const float*)d_in[14];
  const float* modes = (const float*)d_in[15];
  float* out = (float*)d_out;

  float* W = (float*)d_ws;
  float* alloc_= W;                  // B*N
  float* sw_   = alloc_ + B * N;     // B*N
  float* ww_   = sw_ + B * N;        // B*N
  float* ST_   = ww_ + B * N;        // 64
  float* smax_ = ST_ + 64;           // 64
  float* t_    = smax_ + 64;         // B*N*8
  float* sr_   = t_ + B * N * 8;     // B*R*N
  float* rwn_  = sr_ + B * R * N;    // B*R*N
  float* part_ = rwn_ + B * R * N;   // B*32*C*R
  float* upart = part_ + B * 32 * C * R;  // B*32*N*8 = 16MB

  k_alloc<<<B * 8, 1024, 0, stream>>>(usage, wwp, fg, rw, alloc_);
  k_phiw<<<(B * N) / 4, 256, 0, stream>>>(mem, wk, wstr, sw_);
  k_ww<<<B, 1024, 0, stream>>>(sw_, alloc_, ag, wg, prec, rw, ww_, ST_);
  k_linkpass<<<B * 32, 512, 0, stream>>>(link, rw, ww_, t_, upart);
  k_phir<<<(B * N) / 4, 256, 0, stream>>>(mem, rk, ww_, ev, wvec, rs, sr_);
  k_smax<<<B * R, 256, 0, stream>>>(sr_, smax_);
  k_comb<<<(B * N) / 64, 64, 0, stream>>>(link, sr_, t_, upart, ww_, prec, rw,
                                          ST_, smax_, modes, rwn_);
  k_read<<<B * 32, 256, 0, stream>>>(mem, ww_, ev, wvec, rwn_, part_);
  k_final<<<(B * C * R) / 256, 256, 0, stream>>>(part_, out);
}

// Round 5
// 111.429 us; speedup vs baseline: 3.0222x; 1.0112x over previous
//
#include <hip/hip_runtime.h>
#include <math.h>

#define EPS 1e-6f
constexpr int B = 8, N = 2048, C = 256, R = 4;

__device__ __forceinline__ float wred_sum(float v) {
  for (int d = 32; d; d >>= 1) v += __shfl_xor(v, d, 64);
  return v;
}

// ww is pointwise given softmax denominator: wg*(ag*alloc + (1-ag)*exp(sw)/denw)
__device__ __forceinline__ float ww_inline(float sw, float al, float dw,
                                           float agv, float wgv) {
  return wgv * (agv * al + (1.f - agv) * (expf(sw) / dw));
}

// ---- K_pre: blocks 0..255 = sort-free alloc; blocks 256..1279 = phiw + denw atomics
__global__ __launch_bounds__(1024) void k_pre(const float* __restrict__ usage,
    const float* __restrict__ wwp, const float* __restrict__ fg,
    const float* __restrict__ rw, const float* __restrict__ mem,
    const float* __restrict__ wk, const float* __restrict__ wstr,
    float* __restrict__ alloc_, float* __restrict__ sw_, float* __restrict__ denw) {
  __shared__ float2 ulg[N];       // 16KB
  __shared__ float Sp[16][64];    // 4KB
  __shared__ float eacc[16];
  int blk = blockIdx.x;
  int t = threadIdx.x;
  if (blk < 256) {
    // ---- allocation weighting: alloc_i = (1-u_i)*exp2(sum_{pred} log2 u_j)
    int b = blk >> 5, chunk = blk & 31;
    float gx = fg[b * R + 0], gy = fg[b * R + 1], gz = fg[b * R + 2], gw2 = fg[b * R + 3];
    for (int e = t; e < N; e += 1024) {
      float4 r4 = *(const float4*)&rw[(size_t)(b * N + e) * R];
      float psi = (1.f - gx * r4.x) * (1.f - gy * r4.y) * (1.f - gz * r4.z) * (1.f - gw2 * r4.w);
      float us = usage[b * N + e], w = wwp[b * N + e];
      float u = (us + w - us * w) * psi;
      ulg[e] = make_float2(u, log2f(u));
    }
    __syncthreads();
    int i = chunk * 64 + (t & 63);
    int jseg = t >> 6;            // 0..15
    float ui = ulg[i].x;
    float S = 0.f;
    int j0 = jseg * 128;
    #pragma unroll 4
    for (int jj = 0; jj < 128; jj++) {
      int j = j0 + jj;
      float2 v = ulg[j];
      bool sel = (v.x < ui) || (v.x == ui && j < i);
      S += sel ? v.y : 0.f;
    }
    Sp[jseg][t & 63] = S;
    __syncthreads();
    if (t < 64) {
      float tot = 0.f;
      #pragma unroll
      for (int s = 0; s < 16; s++) tot += Sp[s][t];
      int ii = chunk * 64 + t;
      alloc_[b * N + ii] = (1.f - ulg[ii].x) * exp2f(tot);
    }
  } else {
    // ---- phiw: 16 rows per block
    int wv = t >> 6, lane = t & 63;
    int gw = (blk - 256) * 16 + wv;
    int b = gw >> 11, n = gw & (N - 1);
    float4 m4 = *(const float4*)&mem[(size_t)(b * N + n) * C + lane * 4];
    float4 k4 = *(const float4*)&wk[b * C + lane * 4];
    float dot = m4.x * k4.x + m4.y * k4.y + m4.z * k4.z + m4.w * k4.w;
    float nrm = m4.x * m4.x + m4.y * m4.y + m4.z * m4.z + m4.w * m4.w;
    float knr = k4.x * k4.x + k4.y * k4.y + k4.z * k4.z + k4.w * k4.w;
    for (int d = 32; d; d >>= 1) {
      dot += __shfl_xor(dot, d, 64);
      nrm += __shfl_xor(nrm, d, 64);
      knr += __shfl_xor(knr, d, 64);
    }
    if (lane == 0) {
      float phi = dot / (sqrtf(nrm) * sqrtf(knr) + EPS);
      float swv = phi * wstr[b];
      sw_[b * N + n] = swv;
      eacc[wv] = expf(swv);
    }
    __syncthreads();
    if (t == 0) {
      float s = 0.f;
      #pragma unroll
      for (int i = 0; i < 16; i++) s += eacc[i];
      atomicAdd(&denw[b], s);
    }
  }
}

// ---- K_mid: blocks 0..255 linkpass; 256..2303 phir(+denr); 2304..2311 ST
__global__ __launch_bounds__(512) void k_mid(const float* __restrict__ link,
    const float* __restrict__ rw, const float* __restrict__ sw_,
    const float* __restrict__ alloc_, const float* __restrict__ denw,
    const float* __restrict__ ag, const float* __restrict__ wg,
    const float* __restrict__ prec, const float* __restrict__ mem,
    const float* __restrict__ rk, const float* __restrict__ ev,
    const float* __restrict__ wvec, const float* __restrict__ rs,
    float* __restrict__ t_, float* __restrict__ upart, float* __restrict__ sr_,
    float* __restrict__ denr, float* __restrict__ ST_) {
  __shared__ float tred[64][8][8];   // 16KB (linkpass)
  __shared__ float eacc[8][4];       // (phir)
  __shared__ float red8[8][8];       // (ST)
  const int blk = blockIdx.x;
  const int t = threadIdx.x;
  const int lane = t & 63, wv = t >> 6;
  if (blk < 256) {
    // ======== linkpass: 64-row strip, full 2048 columns ========
    const int b = blk >> 5;
    const int strip = blk & 31;
    const int i0 = strip * 64;
    const int jb = t * 4;
    const float agv = ag[b], wgv = wg[b], dw = denw[b];
    float cw[4][8];
    {
      float4 sw4 = *(const float4*)&sw_[b * N + jb];
      float4 al4 = *(const float4*)&alloc_[b * N + jb];
      float wj[4] = { ww_inline(sw4.x, al4.x, dw, agv, wgv),
                      ww_inline(sw4.y, al4.y, dw, agv, wgv),
                      ww_inline(sw4.z, al4.z, dw, agv, wgv),
                      ww_inline(sw4.w, al4.w, dw, agv, wgv) };
      #pragma unroll
      for (int k = 0; k < 4; k++) {
        float4 r4 = *(const float4*)&rw[(size_t)(b * N + jb + k) * R];
        cw[k][0] = r4.x; cw[k][1] = r4.y; cw[k][2] = r4.z; cw[k][3] = r4.w;
        cw[k][4] = wj[k] * r4.x; cw[k][5] = wj[k] * r4.y;
        cw[k][6] = wj[k] * r4.z; cw[k][7] = wj[k] * r4.w;
      }
    }
    float uacc[4][8];
    #pragma unroll
    for (int k = 0; k < 4; k++) {
      #pragma unroll
      for (int r = 0; r < 8; r++) uacc[k][r] = 0.f;
    }
    const float* Lbase = link + (size_t)(b * N + i0) * N;
    for (int ii = 0; ii < 64; ii += 4) {
      float4 La[4];
      #pragma unroll
      for (int m = 0; m < 4; m++)
        La[m] = *(const float4*)(Lbase + (size_t)(ii + m) * N + jb);
      #pragma unroll
      for (int m = 0; m < 4; m++) {
        const int i = i0 + ii + m;
        float4 q = *(const float4*)&rw[(size_t)(b * N + i) * R];
        float wi = ww_inline(sw_[b * N + i], alloc_[b * N + i], dw, agv, wgv);
        float ri[8] = { q.x, q.y, q.z, q.w, wi * q.x, wi * q.y, wi * q.z, wi * q.w };
        float lv[4] = { La[m].x, La[m].y, La[m].z, La[m].w };
        float trow[8] = { 0, 0, 0, 0, 0, 0, 0, 0 };
        #pragma unroll
        for (int k = 0; k < 4; k++) {
          #pragma unroll
          for (int r = 0; r < 8; r++) {
            uacc[k][r] = fmaf(lv[k], ri[r], uacc[k][r]);
            trow[r] = fmaf(lv[k], cw[k][r], trow[r]);
          }
        }
        float nv[4];
        #pragma unroll
        for (int rr = 0; rr < 4; rr++) {
          float a = trow[2 * rr], c = trow[2 * rr + 1];
          float oa = __shfl_xor(a, 1, 64), oc = __shfl_xor(c, 1, 64);
          nv[rr] = (lane & 1) ? (c + oc) : (a + oa);
        }
        float nw[2];
        #pragma unroll
        for (int rr = 0; rr < 2; rr++) {
          float a = nv[2 * rr], c = nv[2 * rr + 1];
          float oa = __shfl_xor(a, 2, 64), oc = __shfl_xor(c, 2, 64);
          nw[rr] = (lane & 2) ? (c + oc) : (a + oa);
        }
        float a2 = nw[0], c2 = nw[1];
        float oa2 = __shfl_xor(a2, 4, 64), oc2 = __shfl_xor(c2, 4, 64);
        float vv = (lane & 4) ? (c2 + oc2) : (a2 + oa2);
        vv += __shfl_xor(vv, 8, 64);
        vv += __shfl_xor(vv, 16, 64);
        vv += __shfl_xor(vv, 32, 64);
        if (lane < 8) tred[ii + m][wv][lane] = vv;
      }
    }
    __syncthreads();
    {
      int i = t & 63, r = t >> 6;
      float s = 0.f;
      #pragma unroll
      for (int w8 = 0; w8 < 8; w8++) s += tred[i][w8][r];
      t_[((size_t)(b * 8 + r)) * N + i0 + i] = s;   // transposed [b][r][n]
    }
    // upart transposed [b][strip][r8][n]
    float* ub = upart + ((size_t)(b * 32 + strip) * 8) * N;
    #pragma unroll
    for (int r = 0; r < 8; r++) {
      float4 v = { uacc[0][r], uacc[1][r], uacc[2][r], uacc[3][r] };
      *(float4*)(ub + (size_t)r * N + jb) = v;
    }
  } else if (blk < 2304) {
    // ======== phir: 8 rows per block + denr atomics ========
    int gw = (blk - 256) * 8 + wv;
    int b = gw >> 11, n = gw & (N - 1);
    const float agv = ag[b], wgv = wg[b], dw = denw[b];
    float w = ww_inline(sw_[b * N + n], alloc_[b * N + n], dw, agv, wgv);
    int c0 = lane * 4;
    float4 m4 = *(const float4*)&mem[(size_t)(b * N + n) * C + c0];
    float4 e4 = *(const float4*)&ev[b * C + c0];
    float4 v4 = *(const float4*)&wvec[b * C + c0];
    float mn[4] = { m4.x * (1.f - w * e4.x) + w * v4.x,
                    m4.y * (1.f - w * e4.y) + w * v4.y,
                    m4.z * (1.f - w * e4.z) + w * v4.z,
                    m4.w * (1.f - w * e4.w) + w * v4.w };
    float dot[4] = { 0, 0, 0, 0 };
    float kn[4] = { 0, 0, 0, 0 };
    float nrm = 0.f;
    #pragma unroll
    for (int ci = 0; ci < 4; ci++) {
      float4 k4 = *(const float4*)&rk[(size_t)(b * C + c0 + ci) * R];
      dot[0] = fmaf(mn[ci], k4.x, dot[0]);
      dot[1] = fmaf(mn[ci], k4.y, dot[1]);
      dot[2] = fmaf(mn[ci], k4.z, dot[2]);
      dot[3] = fmaf(mn[ci], k4.w, dot[3]);
      kn[0] = fmaf(k4.x, k4.x, kn[0]);
      kn[1] = fmaf(k4.y, k4.y, kn[1]);
      kn[2] = fmaf(k4.z, k4.z, kn[2]);
      kn[3] = fmaf(k4.w, k4.w, kn[3]);
      nrm = fmaf(mn[ci], mn[ci], nrm);
    }
    for (int d = 32; d; d >>= 1) {
      dot[0] += __shfl_xor(dot[0], d, 64);
      dot[1] += __shfl_xor(dot[1], d, 64);
      dot[2] += __shfl_xor(dot[2], d, 64);
      dot[3] += __shfl_xor(dot[3], d, 64);
      kn[0] += __shfl_xor(kn[0], d, 64);
      kn[1] += __shfl_xor(kn[1], d, 64);
      kn[2] += __shfl_xor(kn[2], d, 64);
      kn[3] += __shfl_xor(kn[3], d, 64);
      nrm += __shfl_xor(nrm, d, 64);
    }
    if (lane == 0) {
      float mnorm = sqrtf(nrm);
      #pragma unroll
      for (int r = 0; r < 4; r++) {
        float phi = dot[r] / (mnorm * sqrtf(kn[r]) + EPS);
        float sv = phi * rs[b * R + r];
        sr_[(size_t)(b * R + r) * N + n] = sv;
        eacc[wv][r] = expf(sv);
      }
    }
    __syncthreads();
    if (t < 4) {
      float s = 0.f;
      #pragma unroll
      for (int i = 0; i < 8; i++) s += eacc[i][t];
      atomicAdd(&denr[b * R + t], s);
    }
  } else {
    // ======== ST: one block per batch ========
    int b = blk - 2304;
    const float agv = ag[b], wgv = wg[b], dw = denw[b];
    float a[8] = { 0, 0, 0, 0, 0, 0, 0, 0 };
    #pragma unroll
    for (int k = 0; k < 4; k++) {
      int i = t + k * 512;
      float4 r4 = *(const float4*)&rw[(size_t)(b * N + i) * R];
      float pc = prec[b * N + i];
      float w = ww_inline(sw_[b * N + i], alloc_[b * N + i], dw, agv, wgv);
      a[0] = fmaf(pc, r4.x, a[0]); a[1] = fmaf(pc, r4.y, a[1]);
      a[2] = fmaf(pc, r4.z, a[2]); a[3] = fmaf(pc, r4.w, a[3]);
      a[4] = fmaf(w, r4.x, a[4]);  a[5] = fmaf(w, r4.y, a[5]);
      a[6] = fmaf(w, r4.z, a[6]);  a[7] = fmaf(w, r4.w, a[7]);
    }
    #pragma unroll
    for (int r = 0; r < 8; r++) a[r] = wred_sum(a[r]);
    if (lane == 0) {
      #pragma unroll
      for (int r = 0; r < 8; r++) red8[wv][r] = a[r];
    }
    __syncthreads();
    if (t < 8) {
      float s = 0.f;
      #pragma unroll
      for (int i = 0; i < 8; i++) s += red8[i][t];
      ST_[b * 8 + t] = s;
    }
  }
}

// ---- K_combread: strip-reduce u, rwn in LDS, then read_vectors partials
__global__ __launch_bounds__(256) void k_combread(const float* __restrict__ link,
    const float* __restrict__ sw_, const float* __restrict__ alloc_,
    const float* __restrict__ denw, const float* __restrict__ denr,
    const float* __restrict__ ag, const float* __restrict__ wg,
    const float* __restrict__ prec, const float* __restrict__ rw,
    const float* __restrict__ t_, const float* __restrict__ upart,
    const float* __restrict__ sr_, const float* __restrict__ ST_,
    const float* __restrict__ modes, const float* __restrict__ mem,
    const float* __restrict__ ev, const float* __restrict__ wvec,
    float* __restrict__ part_) {
  __shared__ float dgl[64], wloc[64], rwnl[4][64];
  __shared__ float red[4][64][4][4];   // 16KB
  const int blk = blockIdx.x;
  const int b = blk >> 5, chunk = blk & 31;
  const int n0 = chunk * 64;
  const int t = threadIdx.x;
  const int nl = t & 63, r = t >> 6;
  const int n = n0 + nl;
  const float agv = ag[b], wgv = wg[b], dw = denw[b];
  // strip reduction of u-partials (coalesced: [r][n] contiguous)
  float u1 = 0.f, u2 = 0.f;
  const float* up = upart + ((size_t)(b * 32) * 8) * N;
  #pragma unroll 8
  for (int s = 0; s < 32; s++) {
    const float* p = up + ((size_t)s * 8) * N;
    u1 += p[(size_t)r * N + n];
    u2 += p[(size_t)(4 + r) * N + n];
  }
  float pc = prec[b * N + n];
  if (r == 0) {
    float w = ww_inline(sw_[b * N + n], alloc_[b * N + n], dw, agv, wgv);
    float L = link[((size_t)(b * N + n)) * N + n];
    dgl[nl] = (1.f - 2.f * w) * L + w * pc;
    wloc[nl] = w;
  }
  __syncthreads();
  {
    float w = wloc[nl], Dg = dgl[nl];
    float t1 = t_[(size_t)(b * 8 + r) * N + n];
    float t2 = t_[(size_t)(b * 8 + 4 + r) * N + n];
    float sv = sr_[(size_t)(b * R + r) * N + n];
    float cr = expf(sv) / denr[b * R + r];
    float rv = rw[(size_t)(b * N + n) * R + r];
    float S = ST_[b * 8 + r], T = ST_[b * 8 + 4 + r];
    float m0 = modes[(b * 3 + 0) * R + r], m1 = modes[(b * 3 + 1) * R + r],
          m2 = modes[(b * 3 + 2) * R + r];
    float fwd = (1.f - w) * t1 - t2 + w * S - Dg * rv;
    float bwd = (1.f - w) * u1 - u2 + pc * T - Dg * rv;
    rwnl[r][nl] = m0 * bwd + m1 * cr + m2 * fwd;
  }
  __syncthreads();
  // ---- read_vectors partials for this 64-row chunk (rwn from LDS)
  const int sub = r, cg = nl;
  const int c0 = cg * 4;
  float4 e4 = *(const float4*)&ev[b * C + c0];
  float4 v4 = *(const float4*)&wvec[b * C + c0];
  float acc[4][4];
  #pragma unroll
  for (int ci = 0; ci < 4; ci++) {
    #pragma unroll
    for (int rr = 0; rr < 4; rr++) acc[ci][rr] = 0.f;
  }
  for (int m = 0; m < 16; m++) {
    int row = sub * 16 + m;
    int nn = n0 + row;
    float w = wloc[row];
    float4 m4 = *(const float4*)&mem[(size_t)(b * N + nn) * C + c0];
    float mn[4] = { m4.x * (1.f - w * e4.x) + w * v4.x,
                    m4.y * (1.f - w * e4.y) + w * v4.y,
                    m4.z * (1.f - w * e4.z) + w * v4.z,
                    m4.w * (1.f - w * e4.w) + w * v4.w };
    float rv[4] = { rwnl[0][row], rwnl[1][row], rwnl[2][row], rwnl[3][row] };
    #pragma unroll
    for (int ci = 0; ci < 4; ci++) {
      #pragma unroll
      for (int rr = 0; rr < 4; rr++) acc[ci][rr] = fmaf(mn[ci], rv[rr], acc[ci][rr]);
    }
  }
  #pragma unroll
  for (int ci = 0; ci < 4; ci++) {
    #pragma unroll
    for (int rr = 0; rr < 4; rr++) red[sub][cg][ci][rr] = acc[ci][rr];
  }
  __syncthreads();
  if (sub == 0) {
    #pragma unroll
    for (int ci = 0; ci < 4; ci++) {
      #pragma unroll
      for (int rr = 0; rr < 4; rr++) {
        float s = red[0][cg][ci][rr] + red[1][cg][ci][rr] +
                  red[2][cg][ci][rr] + red[3][cg][ci][rr];
        part_[((size_t)blk * C + (c0 + ci)) * R + rr] = s;
      }
    }
  }
}

// ---- K_final: reduce 32 chunk partials -> out [B][C][R]
__global__ void k_final(const float* __restrict__ part_, float* __restrict__ out) {
  int idx = blockIdx.x * 256 + threadIdx.x;
  if (idx >= B * C * R) return;
  int b = idx / (C * R), cr = idx % (C * R);
  float s = 0.f;
  for (int ch = 0; ch < 32; ch++) s += part_[(size_t)(b * 32 + ch) * C * R + cr];
  out[idx] = s;
}

extern "C" void kernel_launch(void* const* d_in, const int* in_sizes, int n_in,
                              void* d_out, int out_size, void* d_ws, size_t ws_size,
                              hipStream_t stream) {
  const float* mem   = (const float*)d_in[0];
  const float* link  = (const float*)d_in[1];
  const float* usage = (const float*)d_in[2];
  const float* rw    = (const float*)d_in[3];
  const float* wwp   = (const float*)d_in[4];
  const float* prec  = (const float*)d_in[5];
  const float* rk    = (const float*)d_in[6];
  const float* rs    = (const float*)d_in[7];
  const float* wk    = (const float*)d_in[8];
  const float* wstr  = (const float*)d_in[9];
  const float* fg    = (const float*)d_in[10];
  const float* ag    = (const float*)d_in[11];
  const float* wg    = (const float*)d_in[12];
  const float* wvec  = (const float*)d_in[13];
  const float* ev    = (const float*)d_in[14];
  const float* modes = (const float*)d_in[15];
  float* out = (float*)d_out;

  float* W = (float*)d_ws;
  float* denw  = W;                   // 8
  float* denr  = W + 8;               // 32 (pad to 64)
  float* alloc_= W + 64;              // B*N
  float* sw_   = alloc_ + B * N;      // B*N
  float* ST_   = sw_ + B * N;         // 64
  float* t_    = ST_ + 64;            // B*8*N
  float* sr_   = t_ + B * 8 * N;      // B*R*N
  float* part_ = sr_ + B * R * N;     // B*32*C*R
  float* upart = part_ + B * 32 * C * R;  // B*32*8*N = 16MB

  (void)hipMemsetAsync(W, 0, 64 * sizeof(float), stream);
  k_pre<<<256 + (B * N) / 16, 1024, 0, stream>>>(usage, wwp, fg, rw, mem, wk, wstr,
                                                 alloc_, sw_, denw);
  k_mid<<<256 + (B * N) / 8 + B, 512, 0, stream>>>(link, rw, sw_, alloc_, denw, ag, wg,
                                                   prec, mem, rk, ev, wvec, rs,
                                                   t_, upart, sr_, denr, ST_);
  k_combread<<<B * 32, 256, 0, stream>>>(link, sw_, alloc_, denw, denr, ag, wg, prec,
                                         rw, t_, upart, sr_, ST_, modes, mem, ev,
                                         wvec, part_);
  k_final<<<(B * C * R) / 256, 256, 0, stream>>>(part_, out);
}